// Round 11
// baseline (584.340 us; speedup 1.0000x reference)
//
#include <hip/hip_runtime.h>

#define N_NODES 50000
#define N_EDGES 800000
#define F_NODE 32
#define F_EDGE 16
#define HID 128
#define DEPTH 4
#define N_GRAPHS 128

#define SCAN_BLOCKS ((N_NODES + 255) / 256)  // 196
#define AGG_GROUPS (N_NODES / 16)            // 3125 (exact: 3125*16 = 50000)

// prep kernel block ranges
#define PREP_HIST_BLOCKS ((N_EDGES + 255) / 256)  // 3125
#define PREP_INIT_BLOCKS 782                      // 782*4 waves*16 nodes = 50048
#define PREP_REPACK_BLOCKS 512
#define PREP_BLOCKS (PREP_HIST_BLOCKS + PREP_INIT_BLOCKS + PREP_REPACK_BLOCKS)

using short8 = __attribute__((ext_vector_type(8))) short;
using f32x4 = __attribute__((ext_vector_type(4))) float;
using v2f = __attribute__((ext_vector_type(2))) float;

__device__ __forceinline__ float bf2f(unsigned short u) {
  return __uint_as_float((unsigned int)u << 16);
}
__device__ __forceinline__ unsigned short f2bf(float f) {
  unsigned int u = __float_as_uint(f);
  u += 0x7fffu + ((u >> 16) & 1u);  // round-to-nearest-even (no NaN in data)
  return (unsigned short)(u >> 16);
}
__device__ __forceinline__ v2f splat2(float s) { return (v2f){s, s}; }
__device__ __forceinline__ v2f unpack2(unsigned int u) {
  v2f r;
  r.x = __uint_as_float(u << 16);           // low ushort  -> col 2l
  r.y = __uint_as_float(u & 0xffff0000u);   // high ushort -> col 2l+1
  return r;
}
__device__ __forceinline__ unsigned int pack2(v2f v) {
  return ((unsigned int)f2bf(v.y) << 16) | (unsigned int)f2bf(v.x);
}

// ---- fused prep: hist | init | repack (independent jobs, one launch) ----
// hist:   blocks [0, 3125)            - edge-dst histogram (atomics)
// init:   blocks [3125, 3907)         - h = relu(x @ Wi + bi); wave holds Wi
//         cols (2l,2l+1) in 32 v2f regs; 16 nodes/wave, coalesced u32 stores.
// repack: blocks [3907, 4419)         - W[k][n] fp32 -> bf16 MFMA B-frag.
//         frag f = t*4+k0; lane l holds B[k0*32+(l>>4)*8+j][t*16+(l&15)].

__global__ __launch_bounds__(256) void prep_kernel(
    const int* __restrict__ dst, int* __restrict__ counts,
    const float* __restrict__ x, const float* __restrict__ Wi,
    const float* __restrict__ bi, unsigned short* __restrict__ h,
    unsigned short* __restrict__ h0, const float* __restrict__ w1,
    const float* __restrict__ w2, unsigned short* __restrict__ wfrag) {
  int blk = blockIdx.x;
  if (blk < PREP_HIST_BLOCKS) {
    int e = blk * 256 + threadIdx.x;
    if (e < N_EDGES) atomicAdd(&counts[dst[e]], 1);
    return;
  }
  if (blk < PREP_HIST_BLOCKS + PREP_INIT_BLOCKS) {
    int b = blk - PREP_HIST_BLOCKS;
    int l = threadIdx.x & 63;
    int wave = __builtin_amdgcn_readfirstlane(threadIdx.x >> 6);
    v2f wv[F_NODE];
#pragma unroll
    for (int k = 0; k < F_NODE; ++k) {
      float2 t = *(const float2*)(Wi + k * HID + 2 * l);
      wv[k] = (v2f){t.x, t.y};
    }
    float2 bt = *(const float2*)(bi + 2 * l);
    v2f bj = (v2f){bt.x, bt.y};
    unsigned int* hu = (unsigned int*)h;
    unsigned int* h0u = (unsigned int*)h0;
    int n0 = (b * 4 + wave) * 16;
    int n1 = n0 + 16;
    if (n1 > N_NODES) n1 = N_NODES;
    for (int node = n0; node < n1; ++node) {
      const float4* xr = (const float4*)(x + (size_t)node * F_NODE);
      v2f acc = bj;
#pragma unroll
      for (int q = 0; q < 8; ++q) {
        float4 xv = xr[q];
        acc = __builtin_elementwise_fma(splat2(xv.x), wv[4 * q + 0], acc);
        acc = __builtin_elementwise_fma(splat2(xv.y), wv[4 * q + 1], acc);
        acc = __builtin_elementwise_fma(splat2(xv.z), wv[4 * q + 2], acc);
        acc = __builtin_elementwise_fma(splat2(xv.w), wv[4 * q + 3], acc);
      }
      acc = __builtin_elementwise_max(acc, splat2(0.f));
      unsigned int p = pack2(acc);
      hu[(size_t)node * 64 + l] = p;
      h0u[(size_t)node * 64 + l] = p;
    }
    return;
  }
  {
    int idx = (blk - PREP_HIST_BLOCKS - PREP_INIT_BLOCKS) * 256 + threadIdx.x;
    if (idx >= 8 * 16384) return;
    int g = idx >> 14;
    int rem = idx & 16383;
    int f = rem >> 9;
    int lane = (rem >> 3) & 63;
    int j = rem & 7;
    int t = f >> 2, k0 = f & 3;
    int k = k0 * 32 + (lane >> 4) * 8 + j;
    int n = t * 16 + (lane & 15);
    int d = g >> 1;
    const float* W = (g & 1) ? (w2 + (size_t)d * HID * HID) : (w1 + (size_t)d * HID * HID);
    wfrag[idx] = f2bf(W[k * HID + n]);
  }
}

// ---------------- CSR scan chain (2 kernels) ----------------

__device__ __forceinline__ int wave_incl_scan(int v, int lane) {
#pragma unroll
  for (int off = 1; off < 64; off <<= 1) {
    int u = __shfl_up(v, off, 64);
    if (lane >= off) v += u;
  }
  return v;
}

__global__ __launch_bounds__(256) void scan_sum_kernel(const int* __restrict__ counts,
                                                       int* __restrict__ bsums) {
  int i = blockIdx.x * 256 + threadIdx.x;
  int v = (i < N_NODES) ? counts[i] : 0;
  int lane = threadIdx.x & 63, wid = threadIdx.x >> 6;
#pragma unroll
  for (int off = 32; off > 0; off >>= 1) v += __shfl_down(v, off, 64);
  __shared__ int ws[4];
  if (lane == 0) ws[wid] = v;
  __syncthreads();
  if (threadIdx.x == 0) bsums[blockIdx.x] = ws[0] + ws[1] + ws[2] + ws[3];
}

// merged scan_mid + scan_write: every block redundantly computes the full
// 196-element block-prefix scan in LDS (196 L2-hot loads, trivial), then
// does its own per-element exclusive scan. Saves one launch + dependency.
__global__ __launch_bounds__(256) void scan_fused_kernel(const int* __restrict__ counts,
                                                         const int* __restrict__ bsums,
                                                         int* __restrict__ row_ptr,
                                                         int* __restrict__ cursor) {
  __shared__ int incl[SCAN_BLOCKS];
  __shared__ int wsum[4];
  __shared__ int wsum2[4];
  int t = threadIdx.x;
  int lane = t & 63, wid = t >> 6;
  // phase A: inclusive scan of bsums[0..195]
  {
    int v = (t < SCAN_BLOCKS) ? bsums[t] : 0;
    int s = wave_incl_scan(v, lane);
    if (lane == 63) wsum[wid] = s;
    __syncthreads();
    int add = 0;
    for (int w = 0; w < wid; ++w) add += wsum[w];
    s += add;
    if (t < SCAN_BLOCKS) incl[t] = s;
  }
  __syncthreads();
  int blockAdd = (blockIdx.x > 0) ? incl[blockIdx.x - 1] : 0;
  if (blockIdx.x == 0 && t == 0) row_ptr[N_NODES] = incl[SCAN_BLOCKS - 1];
  // phase B: per-element exclusive scan within this block
  int i = blockIdx.x * 256 + t;
  int v = (i < N_NODES) ? counts[i] : 0;
  int s = wave_incl_scan(v, lane);
  if (lane == 63) wsum2[wid] = s;
  __syncthreads();
  int add = blockAdd;
  for (int w = 0; w < wid; ++w) add += wsum2[w];
  int excl = s - v + add;
  if (i < N_NODES) {
    row_ptr[i] = excl;
    cursor[i] = excl;
  }
}

// ---- scatter: materialize src/edge_attr in dst-sorted order (fp32, R4 form) ----

__global__ void scatter_kernel(const int* __restrict__ src, const int* __restrict__ dst,
                               const float* __restrict__ edge_attr,
                               int* __restrict__ cursor, int* __restrict__ src_perm,
                               float* __restrict__ ea_perm) {
  int e = blockIdx.x * blockDim.x + threadIdx.x;
  if (e < N_EDGES) {
    int pos = atomicAdd(&cursor[dst[e]], 1);
    src_perm[pos] = src[e];
    const float4* in4 = (const float4*)(edge_attr + (size_t)e * F_EDGE);
    float4 a = in4[0], b = in4[1], c = in4[2], d = in4[3];
    float4* out4 = (float4*)(ea_perm + (size_t)pos * F_EDGE);
    out4[0] = a; out4[1] = b; out4[2] = c; out4[3] = d;
  }
}

// ---- fused per-depth kernel: agg + 2-layer MLP, one block = 16 nodes ----
// R9 config (best measured): 4 waves x 4 nodes, 8-deep gather unroll.
// Gather phase is pinned at ~2 TB/s on the random L2-miss path (VALU+/-,
// ILP+, occupancy+/- all null/negative: R3/R5/R8/R10) -> structural floor.
// New (R11): when do_pool!=0 (last depth), the epilogue atomicAdds
// relu(outT+h0) into pooled[batch[row]] instead of storing hout - deletes
// the pool kernel, its 12.8MB h re-read, and depth3's 12.5MB h write.
// Barriers: 3 (zt ready, z1t ready, outT ready).

#define NODES_PER_WAVE 4
#define AGG_WAVES 4

__device__ __forceinline__ v2f edge_mlp2(const float4* __restrict__ ea,
                                         const v2f w[16], v2f ev) {
  float4 a0 = ea[0], a1 = ea[1], a2 = ea[2], a3 = ea[3];
  ev = __builtin_elementwise_fma(splat2(a0.x), w[0], ev);
  ev = __builtin_elementwise_fma(splat2(a0.y), w[1], ev);
  ev = __builtin_elementwise_fma(splat2(a0.z), w[2], ev);
  ev = __builtin_elementwise_fma(splat2(a0.w), w[3], ev);
  ev = __builtin_elementwise_fma(splat2(a1.x), w[4], ev);
  ev = __builtin_elementwise_fma(splat2(a1.y), w[5], ev);
  ev = __builtin_elementwise_fma(splat2(a1.z), w[6], ev);
  ev = __builtin_elementwise_fma(splat2(a1.w), w[7], ev);
  ev = __builtin_elementwise_fma(splat2(a2.x), w[8], ev);
  ev = __builtin_elementwise_fma(splat2(a2.y), w[9], ev);
  ev = __builtin_elementwise_fma(splat2(a2.z), w[10], ev);
  ev = __builtin_elementwise_fma(splat2(a2.w), w[11], ev);
  ev = __builtin_elementwise_fma(splat2(a3.x), w[12], ev);
  ev = __builtin_elementwise_fma(splat2(a3.y), w[13], ev);
  ev = __builtin_elementwise_fma(splat2(a3.z), w[14], ev);
  ev = __builtin_elementwise_fma(splat2(a3.w), w[15], ev);
  return ev;
}

__global__ __launch_bounds__(256) void depth_kernel(
    const unsigned short* __restrict__ hin, const int* __restrict__ src_perm,
    const float* __restrict__ ea_perm, const int* __restrict__ row_ptr,
    const float* __restrict__ We, const float* __restrict__ be,
    const unsigned short* __restrict__ Wf1, const unsigned short* __restrict__ Wf2,
    const float* __restrict__ b1, const float* __restrict__ b2,
    const unsigned short* __restrict__ h0, unsigned short* __restrict__ hout,
    const int* __restrict__ batch, float* __restrict__ pooled, int do_pool) {
  __shared__ unsigned short zt[16][136];   // agg out (bf16), +8 pad
  __shared__ unsigned short z1t[16][136];  // layer-1 out (bf16)
  __shared__ float outT[16][132];          // layer-2 out (f32)
  int tid = threadIdx.x;
  int l = tid & 63;
  int wave = __builtin_amdgcn_readfirstlane(tid >> 6);  // SGPR, exact
  int m15 = l & 15, quad = l >> 4;
  const unsigned int* h32 = (const unsigned int*)hin;

  // ---- agg phase: zt rows [wave*4, wave*4+4) ----
  v2f w[16];
#pragma unroll
  for (int t = 0; t < F_EDGE; ++t) {
    float2 wv = *(const float2*)(We + t * HID + 2 * l);
    w[t] = (v2f){wv.x, wv.y};
  }
  float2 bv = *(const float2*)(be + 2 * l);
  v2f bj = (v2f){bv.x, bv.y};
  unsigned int* ztu = (unsigned int*)&zt[0][0];  // row stride 68 u32
  int n0 = (blockIdx.x * AGG_WAVES + wave) * NODES_PER_WAVE;
  for (int k = 0; k < NODES_PER_WAVE; ++k) {
    int node = n0 + k;
    int beg = row_ptr[node], end = row_ptr[node + 1];
    v2f hn = unpack2(h32[(size_t)node * 64 + l]);
    v2f acc = splat2(0.f);
    int i = beg;
    for (; i + 8 <= end; i += 8) {
      int s0 = src_perm[i + 0];
      int s1 = src_perm[i + 1];
      int s2 = src_perm[i + 2];
      int s3 = src_perm[i + 3];
      int s4 = src_perm[i + 4];
      int s5 = src_perm[i + 5];
      int s6 = src_perm[i + 6];
      int s7 = src_perm[i + 7];
      unsigned int g0 = h32[(size_t)s0 * 64 + l];
      unsigned int g1 = h32[(size_t)s1 * 64 + l];
      unsigned int g2 = h32[(size_t)s2 * 64 + l];
      unsigned int g3 = h32[(size_t)s3 * 64 + l];
      unsigned int g4 = h32[(size_t)s4 * 64 + l];
      unsigned int g5 = h32[(size_t)s5 * 64 + l];
      unsigned int g6 = h32[(size_t)s6 * 64 + l];
      unsigned int g7 = h32[(size_t)s7 * 64 + l];
      const float4* ea = (const float4*)(ea_perm + (size_t)i * F_EDGE);
      v2f ev0 = edge_mlp2(ea + 0, w, bj);
      v2f ev1 = edge_mlp2(ea + 4, w, bj);
      v2f ev2 = edge_mlp2(ea + 8, w, bj);
      v2f ev3 = edge_mlp2(ea + 12, w, bj);
      v2f ev4 = edge_mlp2(ea + 16, w, bj);
      v2f ev5 = edge_mlp2(ea + 20, w, bj);
      v2f ev6 = edge_mlp2(ea + 24, w, bj);
      v2f ev7 = edge_mlp2(ea + 28, w, bj);
      v2f m0 = unpack2(g0) + ev0;
      v2f m1 = unpack2(g1) + ev1;
      v2f m2 = unpack2(g2) + ev2;
      v2f m3 = unpack2(g3) + ev3;
      v2f m4 = unpack2(g4) + ev4;
      v2f m5 = unpack2(g5) + ev5;
      v2f m6 = unpack2(g6) + ev6;
      v2f m7 = unpack2(g7) + ev7;
      m0 = __builtin_elementwise_max(m0, splat2(0.f));
      m1 = __builtin_elementwise_max(m1, splat2(0.f));
      m2 = __builtin_elementwise_max(m2, splat2(0.f));
      m3 = __builtin_elementwise_max(m3, splat2(0.f));
      m4 = __builtin_elementwise_max(m4, splat2(0.f));
      m5 = __builtin_elementwise_max(m5, splat2(0.f));
      m6 = __builtin_elementwise_max(m6, splat2(0.f));
      m7 = __builtin_elementwise_max(m7, splat2(0.f));
      acc += ((m0 + m1) + (m2 + m3)) + ((m4 + m5) + (m6 + m7));
    }
    for (; i + 4 <= end; i += 4) {
      int s0 = src_perm[i + 0];
      int s1 = src_perm[i + 1];
      int s2 = src_perm[i + 2];
      int s3 = src_perm[i + 3];
      unsigned int g0 = h32[(size_t)s0 * 64 + l];
      unsigned int g1 = h32[(size_t)s1 * 64 + l];
      unsigned int g2 = h32[(size_t)s2 * 64 + l];
      unsigned int g3 = h32[(size_t)s3 * 64 + l];
      const float4* ea = (const float4*)(ea_perm + (size_t)i * F_EDGE);
      v2f ev0 = edge_mlp2(ea + 0, w, bj);
      v2f ev1 = edge_mlp2(ea + 4, w, bj);
      v2f ev2 = edge_mlp2(ea + 8, w, bj);
      v2f ev3 = edge_mlp2(ea + 12, w, bj);
      v2f m0 = unpack2(g0) + ev0;
      v2f m1 = unpack2(g1) + ev1;
      v2f m2 = unpack2(g2) + ev2;
      v2f m3 = unpack2(g3) + ev3;
      m0 = __builtin_elementwise_max(m0, splat2(0.f));
      m1 = __builtin_elementwise_max(m1, splat2(0.f));
      m2 = __builtin_elementwise_max(m2, splat2(0.f));
      m3 = __builtin_elementwise_max(m3, splat2(0.f));
      acc += m0 + m1 + m2 + m3;
    }
    for (; i < end; ++i) {
      int s = src_perm[i];
      unsigned int g = h32[(size_t)s * 64 + l];
      const float4* ea = (const float4*)(ea_perm + (size_t)i * F_EDGE);
      v2f m = unpack2(g) + edge_mlp2(ea, w, bj);
      m = __builtin_elementwise_max(m, splat2(0.f));
      acc += m;
    }
    ztu[(wave * 4 + k) * 68 + l] = pack2(hn + acc);
  }
  __syncthreads();

  // ---- MLP phase 1: z1 = relu(zt @ W1 + b1) -> z1t ----
  float bs1[2], bs2[2];
#pragma unroll
  for (int tt = 0; tt < 2; ++tt) {
    bs1[tt] = b1[(wave * 2 + tt) * 16 + m15];
    bs2[tt] = b2[(wave * 2 + tt) * 16 + m15];
  }
  {
    const unsigned short* ap = &zt[m15][quad * 8];
    short8 a0 = *(const short8*)(ap + 0);
    short8 a1 = *(const short8*)(ap + 32);
    short8 a2 = *(const short8*)(ap + 64);
    short8 a3 = *(const short8*)(ap + 96);
    short8 bw[2][4];
#pragma unroll
    for (int tt = 0; tt < 2; ++tt)
#pragma unroll
      for (int k0 = 0; k0 < 4; ++k0)
        bw[tt][k0] =
            *(const short8*)(Wf1 + (((size_t)(wave * 2 + tt) * 4 + k0) * 64 + l) * 8);
    f32x4 acc2[2];
#pragma unroll
    for (int tt = 0; tt < 2; ++tt) acc2[tt] = (f32x4){0.f, 0.f, 0.f, 0.f};
#pragma unroll
    for (int tt = 0; tt < 2; ++tt) {
      acc2[tt] = __builtin_amdgcn_mfma_f32_16x16x32_bf16(a0, bw[tt][0], acc2[tt], 0, 0, 0);
      acc2[tt] = __builtin_amdgcn_mfma_f32_16x16x32_bf16(a1, bw[tt][1], acc2[tt], 0, 0, 0);
      acc2[tt] = __builtin_amdgcn_mfma_f32_16x16x32_bf16(a2, bw[tt][2], acc2[tt], 0, 0, 0);
      acc2[tt] = __builtin_amdgcn_mfma_f32_16x16x32_bf16(a3, bw[tt][3], acc2[tt], 0, 0, 0);
    }
#pragma unroll
    for (int tt = 0; tt < 2; ++tt) {
      int col = (wave * 2 + tt) * 16 + m15;
#pragma unroll
      for (int r = 0; r < 4; ++r) {
        float v = acc2[tt][r] + bs1[tt];
        v = v > 0.f ? v : 0.f;
        z1t[quad * 4 + r][col] = f2bf(v);
      }
    }
  }
  __syncthreads();

  // ---- MLP phase 2: outT = z1 @ W2 + b2 ----
  {
    const unsigned short* cp = &z1t[m15][quad * 8];
    short8 c0 = *(const short8*)(cp + 0);
    short8 c1 = *(const short8*)(cp + 32);
    short8 c2 = *(const short8*)(cp + 64);
    short8 c3 = *(const short8*)(cp + 96);
    short8 bw[2][4];
#pragma unroll
    for (int tt = 0; tt < 2; ++tt)
#pragma unroll
      for (int k0 = 0; k0 < 4; ++k0)
        bw[tt][k0] =
            *(const short8*)(Wf2 + (((size_t)(wave * 2 + tt) * 4 + k0) * 64 + l) * 8);
    f32x4 acc2[2];
#pragma unroll
    for (int tt = 0; tt < 2; ++tt) acc2[tt] = (f32x4){0.f, 0.f, 0.f, 0.f};
#pragma unroll
    for (int tt = 0; tt < 2; ++tt) {
      acc2[tt] = __builtin_amdgcn_mfma_f32_16x16x32_bf16(c0, bw[tt][0], acc2[tt], 0, 0, 0);
      acc2[tt] = __builtin_amdgcn_mfma_f32_16x16x32_bf16(c1, bw[tt][1], acc2[tt], 0, 0, 0);
      acc2[tt] = __builtin_amdgcn_mfma_f32_16x16x32_bf16(c2, bw[tt][2], acc2[tt], 0, 0, 0);
      acc2[tt] = __builtin_amdgcn_mfma_f32_16x16x32_bf16(c3, bw[tt][3], acc2[tt], 0, 0, 0);
    }
#pragma unroll
    for (int tt = 0; tt < 2; ++tt) {
      int col = (wave * 2 + tt) * 16 + m15;
#pragma unroll
      for (int r = 0; r < 4; ++r) outT[quad * 4 + r][col] = acc2[tt][r] + bs2[tt];
    }
  }
  __syncthreads();

  // ---- epilogue: h = relu(outT + h0); store OR pool-atomically ----
  const unsigned int* h0u = (const unsigned int*)h0;
  unsigned int* hu = (unsigned int*)hout;
  int ec = tid & 63;
  int er0 = tid >> 6;
#pragma unroll
  for (int k = 0; k < 4; ++k) {
    int rl = er0 + 4 * k;  // 0..15
    int rg = blockIdx.x * 16 + rl;
    v2f v = *(const v2f*)&outT[rl][2 * ec];
    v += unpack2(h0u[(size_t)rg * 64 + ec]);
    v = __builtin_elementwise_max(v, splat2(0.f));
    if (do_pool) {
      int g = batch[rg];
      atomicAdd(&pooled[g * HID + 2 * ec], v.x);
      atomicAdd(&pooled[g * HID + 2 * ec + 1], v.y);
    } else {
      hu[(size_t)rg * 64 + ec] = pack2(v);
    }
  }
}

// ---------------- final: out[g] = pooled[g] . ffn_w + ffn_b ----------------

__global__ __launch_bounds__(128) void final_kernel(const float* __restrict__ pooled,
                                                    const float* __restrict__ fw,
                                                    const float* __restrict__ fb,
                                                    float* __restrict__ out) {
  int g = blockIdx.x;
  int j = threadIdx.x;
  float v = pooled[g * HID + j] * fw[j];
#pragma unroll
  for (int off = 32; off > 0; off >>= 1) v += __shfl_down(v, off, 64);
  __shared__ float tmp[2];
  if ((j & 63) == 0) tmp[j >> 6] = v;
  __syncthreads();
  if (j == 0) out[g] = tmp[0] + tmp[1] + fb[0];
}

// ---------------- launch ----------------

extern "C" void kernel_launch(void* const* d_in, const int* in_sizes, int n_in,
                              void* d_out, int out_size, void* d_ws, size_t ws_size,
                              hipStream_t stream) {
  const float* x = (const float*)d_in[0];
  const int* edge_index = (const int*)d_in[1];
  const float* edge_attr = (const float*)d_in[2];
  const int* batch = (const int*)d_in[3];
  const float* init_w = (const float*)d_in[4];
  const float* init_b = (const float*)d_in[5];
  const float* edge_w = (const float*)d_in[6];
  const float* edge_b = (const float*)d_in[7];
  const float* mlp_w1 = (const float*)d_in[8];
  const float* mlp_b1 = (const float*)d_in[9];
  const float* mlp_w2 = (const float*)d_in[10];
  const float* mlp_b2 = (const float*)d_in[11];
  const float* ffn_w = (const float*)d_in[12];
  const float* ffn_b = (const float*)d_in[13];

  const int* srcp = edge_index;
  const int* dstp = edge_index + N_EDGES;

  char* ws = (char*)d_ws;
  auto alloc = [&](size_t bytes) {
    char* p = ws;
    ws += (bytes + 255) & ~(size_t)255;
    return p;
  };
  unsigned short* h_bf = (unsigned short*)alloc((size_t)N_NODES * HID * 2);
  unsigned short* h2_bf = (unsigned short*)alloc((size_t)N_NODES * HID * 2);
  unsigned short* h0_bf = (unsigned short*)alloc((size_t)N_NODES * HID * 2);
  unsigned short* wfrag = (unsigned short*)alloc((size_t)8 * 16384 * 2);
  int* row_ptr = (int*)alloc((size_t)(N_NODES + 1) * 4);
  int* cursor = (int*)alloc((size_t)N_NODES * 4);
  int* counts = (int*)alloc((size_t)N_NODES * 4);
  int* bsums = (int*)alloc((size_t)SCAN_BLOCKS * 4);
  int* src_perm = (int*)alloc((size_t)N_EDGES * 4);
  float* ea_perm = (float*)alloc((size_t)N_EDGES * F_EDGE * 4);
  float* pooled = (float*)alloc((size_t)N_GRAPHS * HID * 4);

  hipMemsetAsync(counts, 0, (size_t)N_NODES * 4, stream);
  hipMemsetAsync(pooled, 0, (size_t)N_GRAPHS * HID * 4, stream);

  prep_kernel<<<PREP_BLOCKS, 256, 0, stream>>>(dstp, counts, x, init_w, init_b, h_bf,
                                               h0_bf, mlp_w1, mlp_w2, wfrag);
  scan_sum_kernel<<<SCAN_BLOCKS, 256, 0, stream>>>(counts, bsums);
  scan_fused_kernel<<<SCAN_BLOCKS, 256, 0, stream>>>(counts, bsums, row_ptr, cursor);
  scatter_kernel<<<(N_EDGES + 255) / 256, 256, 0, stream>>>(srcp, dstp, edge_attr,
                                                            cursor, src_perm, ea_perm);

  unsigned short* hin = h_bf;
  unsigned short* hout = h2_bf;
  for (int d = 0; d < DEPTH; ++d) {
    int do_pool = (d == DEPTH - 1) ? 1 : 0;
    depth_kernel<<<AGG_GROUPS, 256, 0, stream>>>(
        hin, src_perm, ea_perm, row_ptr, edge_w + (size_t)d * F_EDGE * HID,
        edge_b + (size_t)d * HID, wfrag + (size_t)(2 * d) * 16384,
        wfrag + (size_t)(2 * d + 1) * 16384, mlp_b1 + (size_t)d * HID,
        mlp_b2 + (size_t)d * HID, h0_bf, hout, batch, pooled, do_pool);
    unsigned short* t = hin;
    hin = hout;
    hout = t;
  }

  final_kernel<<<N_GRAPHS, 128, 0, stream>>>(pooled, ffn_w, ffn_b, (float*)d_out);
}

// Round 12
// 531.949 us; speedup vs baseline: 1.0985x; 1.0985x over previous
//
#include <hip/hip_runtime.h>

#define N_NODES 50000
#define N_EDGES 800000
#define F_NODE 32
#define F_EDGE 16
#define HID 128
#define DEPTH 4
#define N_GRAPHS 128

#define SCAN_BLOCKS ((N_NODES + 255) / 256)  // 196
#define AGG_GROUPS (N_NODES / 16)            // 3125 (exact: 3125*16 = 50000)

// prep kernel block ranges
#define PREP_HIST_BLOCKS ((N_EDGES + 255) / 256)  // 3125
#define PREP_INIT_BLOCKS 782                      // 782*4 waves*16 nodes = 50048
#define PREP_REPACK_BLOCKS 512
#define PREP_BLOCKS (PREP_HIST_BLOCKS + PREP_INIT_BLOCKS + PREP_REPACK_BLOCKS)

using short8 = __attribute__((ext_vector_type(8))) short;
using f32x4 = __attribute__((ext_vector_type(4))) float;
using v2f = __attribute__((ext_vector_type(2))) float;

__device__ __forceinline__ float bf2f(unsigned short u) {
  return __uint_as_float((unsigned int)u << 16);
}
__device__ __forceinline__ unsigned short f2bf(float f) {
  unsigned int u = __float_as_uint(f);
  u += 0x7fffu + ((u >> 16) & 1u);  // round-to-nearest-even (no NaN in data)
  return (unsigned short)(u >> 16);
}
__device__ __forceinline__ v2f splat2(float s) { return (v2f){s, s}; }
__device__ __forceinline__ v2f unpack2(unsigned int u) {
  v2f r;
  r.x = __uint_as_float(u << 16);           // low ushort  -> col 2l
  r.y = __uint_as_float(u & 0xffff0000u);   // high ushort -> col 2l+1
  return r;
}
__device__ __forceinline__ unsigned int pack2(v2f v) {
  return ((unsigned int)f2bf(v.y) << 16) | (unsigned int)f2bf(v.x);
}

// ---- fused prep: hist | init | repack (independent jobs, one launch) ----
// hist:   blocks [0, 3125)            - edge-dst histogram (atomics)
// init:   blocks [3125, 3907)         - h = relu(x @ Wi + bi); wave holds Wi
//         cols (2l,2l+1) in 32 v2f regs; 16 nodes/wave, coalesced u32 stores.
// repack: blocks [3907, 4419)         - W[k][n] fp32 -> bf16 MFMA B-frag.
//         frag f = t*4+k0; lane l holds B[k0*32+(l>>4)*8+j][t*16+(l&15)].

__global__ __launch_bounds__(256) void prep_kernel(
    const int* __restrict__ dst, int* __restrict__ counts,
    const float* __restrict__ x, const float* __restrict__ Wi,
    const float* __restrict__ bi, unsigned short* __restrict__ h,
    unsigned short* __restrict__ h0, const float* __restrict__ w1,
    const float* __restrict__ w2, unsigned short* __restrict__ wfrag) {
  int blk = blockIdx.x;
  if (blk < PREP_HIST_BLOCKS) {
    int e = blk * 256 + threadIdx.x;
    if (e < N_EDGES) atomicAdd(&counts[dst[e]], 1);
    return;
  }
  if (blk < PREP_HIST_BLOCKS + PREP_INIT_BLOCKS) {
    int b = blk - PREP_HIST_BLOCKS;
    int l = threadIdx.x & 63;
    int wave = __builtin_amdgcn_readfirstlane(threadIdx.x >> 6);
    v2f wv[F_NODE];
#pragma unroll
    for (int k = 0; k < F_NODE; ++k) {
      float2 t = *(const float2*)(Wi + k * HID + 2 * l);
      wv[k] = (v2f){t.x, t.y};
    }
    float2 bt = *(const float2*)(bi + 2 * l);
    v2f bj = (v2f){bt.x, bt.y};
    unsigned int* hu = (unsigned int*)h;
    unsigned int* h0u = (unsigned int*)h0;
    int n0 = (b * 4 + wave) * 16;
    int n1 = n0 + 16;
    if (n1 > N_NODES) n1 = N_NODES;
    for (int node = n0; node < n1; ++node) {
      const float4* xr = (const float4*)(x + (size_t)node * F_NODE);
      v2f acc = bj;
#pragma unroll
      for (int q = 0; q < 8; ++q) {
        float4 xv = xr[q];
        acc = __builtin_elementwise_fma(splat2(xv.x), wv[4 * q + 0], acc);
        acc = __builtin_elementwise_fma(splat2(xv.y), wv[4 * q + 1], acc);
        acc = __builtin_elementwise_fma(splat2(xv.z), wv[4 * q + 2], acc);
        acc = __builtin_elementwise_fma(splat2(xv.w), wv[4 * q + 3], acc);
      }
      acc = __builtin_elementwise_max(acc, splat2(0.f));
      unsigned int p = pack2(acc);
      hu[(size_t)node * 64 + l] = p;
      h0u[(size_t)node * 64 + l] = p;
    }
    return;
  }
  {
    int idx = (blk - PREP_HIST_BLOCKS - PREP_INIT_BLOCKS) * 256 + threadIdx.x;
    if (idx >= 8 * 16384) return;
    int g = idx >> 14;
    int rem = idx & 16383;
    int f = rem >> 9;
    int lane = (rem >> 3) & 63;
    int j = rem & 7;
    int t = f >> 2, k0 = f & 3;
    int k = k0 * 32 + (lane >> 4) * 8 + j;
    int n = t * 16 + (lane & 15);
    int d = g >> 1;
    const float* W = (g & 1) ? (w2 + (size_t)d * HID * HID) : (w1 + (size_t)d * HID * HID);
    wfrag[idx] = f2bf(W[k * HID + n]);
  }
}

// ---------------- CSR scan chain (2 kernels) ----------------

__device__ __forceinline__ int wave_incl_scan(int v, int lane) {
#pragma unroll
  for (int off = 1; off < 64; off <<= 1) {
    int u = __shfl_up(v, off, 64);
    if (lane >= off) v += u;
  }
  return v;
}

__global__ __launch_bounds__(256) void scan_sum_kernel(const int* __restrict__ counts,
                                                       int* __restrict__ bsums) {
  int i = blockIdx.x * 256 + threadIdx.x;
  int v = (i < N_NODES) ? counts[i] : 0;
  int lane = threadIdx.x & 63, wid = threadIdx.x >> 6;
#pragma unroll
  for (int off = 32; off > 0; off >>= 1) v += __shfl_down(v, off, 64);
  __shared__ int ws[4];
  if (lane == 0) ws[wid] = v;
  __syncthreads();
  if (threadIdx.x == 0) bsums[blockIdx.x] = ws[0] + ws[1] + ws[2] + ws[3];
}

// merged scan_mid + scan_write: every block redundantly computes the full
// 196-element block-prefix scan in LDS (196 L2-hot loads, trivial), then
// does its own per-element exclusive scan. Saves one launch + dependency.
__global__ __launch_bounds__(256) void scan_fused_kernel(const int* __restrict__ counts,
                                                         const int* __restrict__ bsums,
                                                         int* __restrict__ row_ptr,
                                                         int* __restrict__ cursor) {
  __shared__ int incl[SCAN_BLOCKS];
  __shared__ int wsum[4];
  __shared__ int wsum2[4];
  int t = threadIdx.x;
  int lane = t & 63, wid = t >> 6;
  // phase A: inclusive scan of bsums[0..195]
  {
    int v = (t < SCAN_BLOCKS) ? bsums[t] : 0;
    int s = wave_incl_scan(v, lane);
    if (lane == 63) wsum[wid] = s;
    __syncthreads();
    int add = 0;
    for (int w = 0; w < wid; ++w) add += wsum[w];
    s += add;
    if (t < SCAN_BLOCKS) incl[t] = s;
  }
  __syncthreads();
  int blockAdd = (blockIdx.x > 0) ? incl[blockIdx.x - 1] : 0;
  if (blockIdx.x == 0 && t == 0) row_ptr[N_NODES] = incl[SCAN_BLOCKS - 1];
  // phase B: per-element exclusive scan within this block
  int i = blockIdx.x * 256 + t;
  int v = (i < N_NODES) ? counts[i] : 0;
  int s = wave_incl_scan(v, lane);
  if (lane == 63) wsum2[wid] = s;
  __syncthreads();
  int add = blockAdd;
  for (int w = 0; w < wid; ++w) add += wsum2[w];
  int excl = s - v + add;
  if (i < N_NODES) {
    row_ptr[i] = excl;
    cursor[i] = excl;
  }
}

// ---- scatter: materialize src/edge_attr in dst-sorted order (fp32, R4 form) ----
// Random 64B records pay the 128B write-allocate floor (WRITE ~2x payload);
// all costed alternatives (bf16 perm R3/R5, gather-side, atomic agg) worse.

__global__ void scatter_kernel(const int* __restrict__ src, const int* __restrict__ dst,
                               const float* __restrict__ edge_attr,
                               int* __restrict__ cursor, int* __restrict__ src_perm,
                               float* __restrict__ ea_perm) {
  int e = blockIdx.x * blockDim.x + threadIdx.x;
  if (e < N_EDGES) {
    int pos = atomicAdd(&cursor[dst[e]], 1);
    src_perm[pos] = src[e];
    const float4* in4 = (const float4*)(edge_attr + (size_t)e * F_EDGE);
    float4 a = in4[0], b = in4[1], c = in4[2], d = in4[3];
    float4* out4 = (float4*)(ea_perm + (size_t)pos * F_EDGE);
    out4[0] = a; out4[1] = b; out4[2] = c; out4[3] = d;
  }
}

// ---- fused per-depth kernel: agg + 2-layer MLP, one block = 16 nodes ----
// R9 config (best measured): 4 waves x 4 nodes, 8-deep gather unroll.
// Gather phase pinned at ~2.6 TB/s combined L2+HBM random-row service
// (VALU+/-, ILP+, occupancy+/- all null/negative: R3/R5/R8/R10) ->
// structural floor ~78us. Pool fusion into the epilogue was tried (R11):
// +63us from 6.4M same-address atomics -> reverted; pool_kernel restored.
// Barriers: 3 (zt ready, z1t ready, outT ready).

#define NODES_PER_WAVE 4
#define AGG_WAVES 4

__device__ __forceinline__ v2f edge_mlp2(const float4* __restrict__ ea,
                                         const v2f w[16], v2f ev) {
  float4 a0 = ea[0], a1 = ea[1], a2 = ea[2], a3 = ea[3];
  ev = __builtin_elementwise_fma(splat2(a0.x), w[0], ev);
  ev = __builtin_elementwise_fma(splat2(a0.y), w[1], ev);
  ev = __builtin_elementwise_fma(splat2(a0.z), w[2], ev);
  ev = __builtin_elementwise_fma(splat2(a0.w), w[3], ev);
  ev = __builtin_elementwise_fma(splat2(a1.x), w[4], ev);
  ev = __builtin_elementwise_fma(splat2(a1.y), w[5], ev);
  ev = __builtin_elementwise_fma(splat2(a1.z), w[6], ev);
  ev = __builtin_elementwise_fma(splat2(a1.w), w[7], ev);
  ev = __builtin_elementwise_fma(splat2(a2.x), w[8], ev);
  ev = __builtin_elementwise_fma(splat2(a2.y), w[9], ev);
  ev = __builtin_elementwise_fma(splat2(a2.z), w[10], ev);
  ev = __builtin_elementwise_fma(splat2(a2.w), w[11], ev);
  ev = __builtin_elementwise_fma(splat2(a3.x), w[12], ev);
  ev = __builtin_elementwise_fma(splat2(a3.y), w[13], ev);
  ev = __builtin_elementwise_fma(splat2(a3.z), w[14], ev);
  ev = __builtin_elementwise_fma(splat2(a3.w), w[15], ev);
  return ev;
}

__global__ __launch_bounds__(256) void depth_kernel(
    const unsigned short* __restrict__ hin, const int* __restrict__ src_perm,
    const float* __restrict__ ea_perm, const int* __restrict__ row_ptr,
    const float* __restrict__ We, const float* __restrict__ be,
    const unsigned short* __restrict__ Wf1, const unsigned short* __restrict__ Wf2,
    const float* __restrict__ b1, const float* __restrict__ b2,
    const unsigned short* __restrict__ h0, unsigned short* __restrict__ hout) {
  __shared__ unsigned short zt[16][136];   // agg out (bf16), +8 pad
  __shared__ unsigned short z1t[16][136];  // layer-1 out (bf16)
  __shared__ float outT[16][132];          // layer-2 out (f32)
  int tid = threadIdx.x;
  int l = tid & 63;
  int wave = __builtin_amdgcn_readfirstlane(tid >> 6);  // SGPR, exact
  int m15 = l & 15, quad = l >> 4;
  const unsigned int* h32 = (const unsigned int*)hin;

  // ---- agg phase: zt rows [wave*4, wave*4+4) ----
  v2f w[16];
#pragma unroll
  for (int t = 0; t < F_EDGE; ++t) {
    float2 wv = *(const float2*)(We + t * HID + 2 * l);
    w[t] = (v2f){wv.x, wv.y};
  }
  float2 bv = *(const float2*)(be + 2 * l);
  v2f bj = (v2f){bv.x, bv.y};
  unsigned int* ztu = (unsigned int*)&zt[0][0];  // row stride 68 u32
  int n0 = (blockIdx.x * AGG_WAVES + wave) * NODES_PER_WAVE;
  for (int k = 0; k < NODES_PER_WAVE; ++k) {
    int node = n0 + k;
    int beg = row_ptr[node], end = row_ptr[node + 1];
    v2f hn = unpack2(h32[(size_t)node * 64 + l]);
    v2f acc = splat2(0.f);
    int i = beg;
    for (; i + 8 <= end; i += 8) {
      int s0 = src_perm[i + 0];
      int s1 = src_perm[i + 1];
      int s2 = src_perm[i + 2];
      int s3 = src_perm[i + 3];
      int s4 = src_perm[i + 4];
      int s5 = src_perm[i + 5];
      int s6 = src_perm[i + 6];
      int s7 = src_perm[i + 7];
      unsigned int g0 = h32[(size_t)s0 * 64 + l];
      unsigned int g1 = h32[(size_t)s1 * 64 + l];
      unsigned int g2 = h32[(size_t)s2 * 64 + l];
      unsigned int g3 = h32[(size_t)s3 * 64 + l];
      unsigned int g4 = h32[(size_t)s4 * 64 + l];
      unsigned int g5 = h32[(size_t)s5 * 64 + l];
      unsigned int g6 = h32[(size_t)s6 * 64 + l];
      unsigned int g7 = h32[(size_t)s7 * 64 + l];
      const float4* ea = (const float4*)(ea_perm + (size_t)i * F_EDGE);
      v2f ev0 = edge_mlp2(ea + 0, w, bj);
      v2f ev1 = edge_mlp2(ea + 4, w, bj);
      v2f ev2 = edge_mlp2(ea + 8, w, bj);
      v2f ev3 = edge_mlp2(ea + 12, w, bj);
      v2f ev4 = edge_mlp2(ea + 16, w, bj);
      v2f ev5 = edge_mlp2(ea + 20, w, bj);
      v2f ev6 = edge_mlp2(ea + 24, w, bj);
      v2f ev7 = edge_mlp2(ea + 28, w, bj);
      v2f m0 = unpack2(g0) + ev0;
      v2f m1 = unpack2(g1) + ev1;
      v2f m2 = unpack2(g2) + ev2;
      v2f m3 = unpack2(g3) + ev3;
      v2f m4 = unpack2(g4) + ev4;
      v2f m5 = unpack2(g5) + ev5;
      v2f m6 = unpack2(g6) + ev6;
      v2f m7 = unpack2(g7) + ev7;
      m0 = __builtin_elementwise_max(m0, splat2(0.f));
      m1 = __builtin_elementwise_max(m1, splat2(0.f));
      m2 = __builtin_elementwise_max(m2, splat2(0.f));
      m3 = __builtin_elementwise_max(m3, splat2(0.f));
      m4 = __builtin_elementwise_max(m4, splat2(0.f));
      m5 = __builtin_elementwise_max(m5, splat2(0.f));
      m6 = __builtin_elementwise_max(m6, splat2(0.f));
      m7 = __builtin_elementwise_max(m7, splat2(0.f));
      acc += ((m0 + m1) + (m2 + m3)) + ((m4 + m5) + (m6 + m7));
    }
    for (; i + 4 <= end; i += 4) {
      int s0 = src_perm[i + 0];
      int s1 = src_perm[i + 1];
      int s2 = src_perm[i + 2];
      int s3 = src_perm[i + 3];
      unsigned int g0 = h32[(size_t)s0 * 64 + l];
      unsigned int g1 = h32[(size_t)s1 * 64 + l];
      unsigned int g2 = h32[(size_t)s2 * 64 + l];
      unsigned int g3 = h32[(size_t)s3 * 64 + l];
      const float4* ea = (const float4*)(ea_perm + (size_t)i * F_EDGE);
      v2f ev0 = edge_mlp2(ea + 0, w, bj);
      v2f ev1 = edge_mlp2(ea + 4, w, bj);
      v2f ev2 = edge_mlp2(ea + 8, w, bj);
      v2f ev3 = edge_mlp2(ea + 12, w, bj);
      v2f m0 = unpack2(g0) + ev0;
      v2f m1 = unpack2(g1) + ev1;
      v2f m2 = unpack2(g2) + ev2;
      v2f m3 = unpack2(g3) + ev3;
      m0 = __builtin_elementwise_max(m0, splat2(0.f));
      m1 = __builtin_elementwise_max(m1, splat2(0.f));
      m2 = __builtin_elementwise_max(m2, splat2(0.f));
      m3 = __builtin_elementwise_max(m3, splat2(0.f));
      acc += m0 + m1 + m2 + m3;
    }
    for (; i < end; ++i) {
      int s = src_perm[i];
      unsigned int g = h32[(size_t)s * 64 + l];
      const float4* ea = (const float4*)(ea_perm + (size_t)i * F_EDGE);
      v2f m = unpack2(g) + edge_mlp2(ea, w, bj);
      m = __builtin_elementwise_max(m, splat2(0.f));
      acc += m;
    }
    ztu[(wave * 4 + k) * 68 + l] = pack2(hn + acc);
  }
  __syncthreads();

  // ---- MLP phase 1: z1 = relu(zt @ W1 + b1) -> z1t ----
  float bs1[2], bs2[2];
#pragma unroll
  for (int tt = 0; tt < 2; ++tt) {
    bs1[tt] = b1[(wave * 2 + tt) * 16 + m15];
    bs2[tt] = b2[(wave * 2 + tt) * 16 + m15];
  }
  {
    const unsigned short* ap = &zt[m15][quad * 8];
    short8 a0 = *(const short8*)(ap + 0);
    short8 a1 = *(const short8*)(ap + 32);
    short8 a2 = *(const short8*)(ap + 64);
    short8 a3 = *(const short8*)(ap + 96);
    short8 bw[2][4];
#pragma unroll
    for (int tt = 0; tt < 2; ++tt)
#pragma unroll
      for (int k0 = 0; k0 < 4; ++k0)
        bw[tt][k0] =
            *(const short8*)(Wf1 + (((size_t)(wave * 2 + tt) * 4 + k0) * 64 + l) * 8);
    f32x4 acc2[2];
#pragma unroll
    for (int tt = 0; tt < 2; ++tt) acc2[tt] = (f32x4){0.f, 0.f, 0.f, 0.f};
#pragma unroll
    for (int tt = 0; tt < 2; ++tt) {
      acc2[tt] = __builtin_amdgcn_mfma_f32_16x16x32_bf16(a0, bw[tt][0], acc2[tt], 0, 0, 0);
      acc2[tt] = __builtin_amdgcn_mfma_f32_16x16x32_bf16(a1, bw[tt][1], acc2[tt], 0, 0, 0);
      acc2[tt] = __builtin_amdgcn_mfma_f32_16x16x32_bf16(a2, bw[tt][2], acc2[tt], 0, 0, 0);
      acc2[tt] = __builtin_amdgcn_mfma_f32_16x16x32_bf16(a3, bw[tt][3], acc2[tt], 0, 0, 0);
    }
#pragma unroll
    for (int tt = 0; tt < 2; ++tt) {
      int col = (wave * 2 + tt) * 16 + m15;
#pragma unroll
      for (int r = 0; r < 4; ++r) {
        float v = acc2[tt][r] + bs1[tt];
        v = v > 0.f ? v : 0.f;
        z1t[quad * 4 + r][col] = f2bf(v);
      }
    }
  }
  __syncthreads();

  // ---- MLP phase 2: outT = z1 @ W2 + b2 ----
  {
    const unsigned short* cp = &z1t[m15][quad * 8];
    short8 c0 = *(const short8*)(cp + 0);
    short8 c1 = *(const short8*)(cp + 32);
    short8 c2 = *(const short8*)(cp + 64);
    short8 c3 = *(const short8*)(cp + 96);
    short8 bw[2][4];
#pragma unroll
    for (int tt = 0; tt < 2; ++tt)
#pragma unroll
      for (int k0 = 0; k0 < 4; ++k0)
        bw[tt][k0] =
            *(const short8*)(Wf2 + (((size_t)(wave * 2 + tt) * 4 + k0) * 64 + l) * 8);
    f32x4 acc2[2];
#pragma unroll
    for (int tt = 0; tt < 2; ++tt) acc2[tt] = (f32x4){0.f, 0.f, 0.f, 0.f};
#pragma unroll
    for (int tt = 0; tt < 2; ++tt) {
      acc2[tt] = __builtin_amdgcn_mfma_f32_16x16x32_bf16(c0, bw[tt][0], acc2[tt], 0, 0, 0);
      acc2[tt] = __builtin_amdgcn_mfma_f32_16x16x32_bf16(c1, bw[tt][1], acc2[tt], 0, 0, 0);
      acc2[tt] = __builtin_amdgcn_mfma_f32_16x16x32_bf16(c2, bw[tt][2], acc2[tt], 0, 0, 0);
      acc2[tt] = __builtin_amdgcn_mfma_f32_16x16x32_bf16(c3, bw[tt][3], acc2[tt], 0, 0, 0);
    }
#pragma unroll
    for (int tt = 0; tt < 2; ++tt) {
      int col = (wave * 2 + tt) * 16 + m15;
#pragma unroll
      for (int r = 0; r < 4; ++r) outT[quad * 4 + r][col] = acc2[tt][r] + bs2[tt];
    }
  }
  __syncthreads();

  // ---- epilogue: h = relu(outT + h0), linear coalesced ----
  const unsigned int* h0u = (const unsigned int*)h0;
  unsigned int* hu = (unsigned int*)hout;
  int ec = tid & 63;
  int er0 = tid >> 6;
#pragma unroll
  for (int k = 0; k < 4; ++k) {
    int rl = er0 + 4 * k;  // 0..15
    int rg = blockIdx.x * 16 + rl;
    v2f v = *(const v2f*)&outT[rl][2 * ec];
    v += unpack2(h0u[(size_t)rg * 64 + ec]);
    v = __builtin_elementwise_max(v, splat2(0.f));
    hu[(size_t)rg * 64 + ec] = pack2(v);
  }
}

// ---------------- pooling (batch is sorted), h in bf16 ----------------
// Per-wave register pre-reduction over 8 nodes, atomics only at graph
// boundaries (~0.8M atomics total) - the R11 fused variant's 6.4M
// same-address atomics serialized in L2 (+63us); this form is ~5us.

#define POOL_NPW 8

__global__ __launch_bounds__(256) void pool_kernel(const unsigned short* __restrict__ h,
                                                   const int* __restrict__ batch,
                                                   float* __restrict__ pooled) {
  int l = threadIdx.x & 63;
  int wave = __builtin_amdgcn_readfirstlane(threadIdx.x >> 6);
  const unsigned int* h32 = (const unsigned int*)h;
  int n0 = (blockIdx.x * 4 + wave) * POOL_NPW;
  if (n0 >= N_NODES) return;
  int n1 = n0 + POOL_NPW;
  if (n1 > N_NODES) n1 = N_NODES;
  int cur = batch[n0];
  v2f acc = splat2(0.f);
  for (int n = n0; n < n1; ++n) {
    int b = batch[n];
    if (b != cur) {
      atomicAdd(&pooled[cur * HID + 2 * l], acc.x);
      atomicAdd(&pooled[cur * HID + 2 * l + 1], acc.y);
      acc = splat2(0.f);
      cur = b;
    }
    acc += unpack2(h32[(size_t)n * 64 + l]);
  }
  atomicAdd(&pooled[cur * HID + 2 * l], acc.x);
  atomicAdd(&pooled[cur * HID + 2 * l + 1], acc.y);
}

// ---------------- final: out[g] = pooled[g] . ffn_w + ffn_b ----------------

__global__ __launch_bounds__(128) void final_kernel(const float* __restrict__ pooled,
                                                    const float* __restrict__ fw,
                                                    const float* __restrict__ fb,
                                                    float* __restrict__ out) {
  int g = blockIdx.x;
  int j = threadIdx.x;
  float v = pooled[g * HID + j] * fw[j];
#pragma unroll
  for (int off = 32; off > 0; off >>= 1) v += __shfl_down(v, off, 64);
  __shared__ float tmp[2];
  if ((j & 63) == 0) tmp[j >> 6] = v;
  __syncthreads();
  if (j == 0) out[g] = tmp[0] + tmp[1] + fb[0];
}

// ---------------- launch ----------------

extern "C" void kernel_launch(void* const* d_in, const int* in_sizes, int n_in,
                              void* d_out, int out_size, void* d_ws, size_t ws_size,
                              hipStream_t stream) {
  const float* x = (const float*)d_in[0];
  const int* edge_index = (const int*)d_in[1];
  const float* edge_attr = (const float*)d_in[2];
  const int* batch = (const int*)d_in[3];
  const float* init_w = (const float*)d_in[4];
  const float* init_b = (const float*)d_in[5];
  const float* edge_w = (const float*)d_in[6];
  const float* edge_b = (const float*)d_in[7];
  const float* mlp_w1 = (const float*)d_in[8];
  const float* mlp_b1 = (const float*)d_in[9];
  const float* mlp_w2 = (const float*)d_in[10];
  const float* mlp_b2 = (const float*)d_in[11];
  const float* ffn_w = (const float*)d_in[12];
  const float* ffn_b = (const float*)d_in[13];

  const int* srcp = edge_index;
  const int* dstp = edge_index + N_EDGES;

  char* ws = (char*)d_ws;
  auto alloc = [&](size_t bytes) {
    char* p = ws;
    ws += (bytes + 255) & ~(size_t)255;
    return p;
  };
  unsigned short* h_bf = (unsigned short*)alloc((size_t)N_NODES * HID * 2);
  unsigned short* h2_bf = (unsigned short*)alloc((size_t)N_NODES * HID * 2);
  unsigned short* h0_bf = (unsigned short*)alloc((size_t)N_NODES * HID * 2);
  unsigned short* wfrag = (unsigned short*)alloc((size_t)8 * 16384 * 2);
  int* row_ptr = (int*)alloc((size_t)(N_NODES + 1) * 4);
  int* cursor = (int*)alloc((size_t)N_NODES * 4);
  int* counts = (int*)alloc((size_t)N_NODES * 4);
  int* bsums = (int*)alloc((size_t)SCAN_BLOCKS * 4);
  int* src_perm = (int*)alloc((size_t)N_EDGES * 4);
  float* ea_perm = (float*)alloc((size_t)N_EDGES * F_EDGE * 4);
  float* pooled = (float*)alloc((size_t)N_GRAPHS * HID * 4);

  hipMemsetAsync(counts, 0, (size_t)N_NODES * 4, stream);
  hipMemsetAsync(pooled, 0, (size_t)N_GRAPHS * HID * 4, stream);

  prep_kernel<<<PREP_BLOCKS, 256, 0, stream>>>(dstp, counts, x, init_w, init_b, h_bf,
                                               h0_bf, mlp_w1, mlp_w2, wfrag);
  scan_sum_kernel<<<SCAN_BLOCKS, 256, 0, stream>>>(counts, bsums);
  scan_fused_kernel<<<SCAN_BLOCKS, 256, 0, stream>>>(counts, bsums, row_ptr, cursor);
  scatter_kernel<<<(N_EDGES + 255) / 256, 256, 0, stream>>>(srcp, dstp, edge_attr,
                                                            cursor, src_perm, ea_perm);

  unsigned short* hin = h_bf;
  unsigned short* hout = h2_bf;
  for (int d = 0; d < DEPTH; ++d) {
    depth_kernel<<<AGG_GROUPS, 256, 0, stream>>>(
        hin, src_perm, ea_perm, row_ptr, edge_w + (size_t)d * F_EDGE * HID,
        edge_b + (size_t)d * HID, wfrag + (size_t)(2 * d) * 16384,
        wfrag + (size_t)(2 * d + 1) * 16384, mlp_b1 + (size_t)d * HID,
        mlp_b2 + (size_t)d * HID, h0_bf, hout);
    unsigned short* t = hin;
    hin = hout;
    hout = t;
  }
  // DEPTH even -> final h is back in h_bf (== hin)

  const int POOL_NPB = 4 * POOL_NPW;  // 32 nodes per block
  pool_kernel<<<(N_NODES + POOL_NPB - 1) / POOL_NPB, 256, 0, stream>>>(hin, batch,
                                                                       pooled);
  final_kernel<<<N_GRAPHS, 128, 0, stream>>>(pooled, ffn_w, ffn_b, (float*)d_out);
}